// Round 1
// baseline (106.690 us; speedup 1.0000x reference)
//
#include <hip/hip_runtime.h>
#include <math.h>

#define NWIRE   12
#define DIM     4096      // 2^12
#define NPAIR   2048
#define THREADS 256

// Apply a general complex 2x2 gate on wire w. State in LDS as sr/si (real/imag).
__device__ __forceinline__ void gate1q(float* sr, float* si, int w,
    float m00r, float m00i, float m01r, float m01i,
    float m10r, float m10i, float m11r, float m11i)
{
    const int mask = 1 << (11 - w);
    const int lo   = mask - 1;
    for (int p = threadIdx.x; p < NPAIR; p += THREADS) {
        int i0 = ((p & ~lo) << 1) | (p & lo);
        int i1 = i0 | mask;
        float a0r = sr[i0], a0i = si[i0];
        float a1r = sr[i1], a1i = si[i1];
        sr[i0] = m00r*a0r - m00i*a0i + m01r*a1r - m01i*a1i;
        si[i0] = m00r*a0i + m00i*a0r + m01r*a1i + m01i*a1r;
        sr[i1] = m10r*a0r - m10i*a0i + m11r*a1r - m11i*a1i;
        si[i1] = m10r*a0i + m10i*a0r + m11r*a1i + m11i*a1r;
    }
    __syncthreads();
}

// Controlled 2x2 gate: apply on target t where control wire c bit == 1.
__device__ __forceinline__ void gateCtrl(float* sr, float* si, int c, int t,
    float m00r, float m00i, float m01r, float m01i,
    float m10r, float m10i, float m11r, float m11i)
{
    const int tmask = 1 << (11 - t);
    const int cmask = 1 << (11 - c);
    const int lo    = tmask - 1;
    for (int p = threadIdx.x; p < NPAIR; p += THREADS) {
        int i0 = ((p & ~lo) << 1) | (p & lo);
        if (i0 & cmask) {
            int i1 = i0 | tmask;
            float a0r = sr[i0], a0i = si[i0];
            float a1r = sr[i1], a1i = si[i1];
            sr[i0] = m00r*a0r - m00i*a0i + m01r*a1r - m01i*a1i;
            si[i0] = m00r*a0i + m00i*a0r + m01r*a1i + m01i*a1r;
            sr[i1] = m10r*a0r - m10i*a0i + m11r*a1r - m11i*a1i;
            si[i1] = m10r*a0i + m10i*a0r + m11r*a1i + m11i*a1r;
        }
    }
    __syncthreads();
}

__device__ __forceinline__ void gateRY(float* sr, float* si, int w, float theta)
{
    float ss, cc; sincosf(0.5f * theta, &ss, &cc);
    gate1q(sr, si, w, cc, 0.f, -ss, 0.f, ss, 0.f, cc, 0.f);
}

__device__ __forceinline__ void gateCRY(float* sr, float* si, int c, int t, float theta)
{
    float ss, cc; sincosf(0.5f * theta, &ss, &cc);
    gateCtrl(sr, si, c, t, cc, 0.f, -ss, 0.f, ss, 0.f, cc, 0.f);
}

__global__ __launch_bounds__(THREADS)
void qsim_kernel(const float* __restrict__ cov,
                 const float* __restrict__ dose,
                 const float* __restrict__ theta,
                 float* __restrict__ out, int B)
{
    __shared__ float sr[DIM];
    __shared__ float si[DIM];
    const int b   = blockIdx.x;
    const int tid = threadIdx.x;

    // init |0...0>
    for (int i = tid; i < DIM; i += THREADS) { sr[i] = 0.f; si[i] = 0.f; }
    if (tid == 0) sr[0] = 1.0f;
    __syncthreads();

    // input encoding: RY(inputs[i]) on wires 0,1,2
    {
        float ang0 = cov[b*2 + 0];
        float ang1 = cov[b*2 + 1];
        float ang2 = dose[b];
        gateRY(sr, si, 0, ang0);
        gateRY(sr, si, 1, ang1);
        gateRY(sr, si, 2, ang2);
    }

    // theta layout: init_euler[2,3,3]@0, pk_coup[2,3,5]@18, pd_coup[2,3,4]@48,
    //               pk_local[2,5]@72, pd_local[2,4]@82
    for (int l = 0; l < 2; ++l) {
        for (int q = 0; q < 3; ++q) {
            float e0 = theta[l*9 + q*3 + 0];
            float e1 = theta[l*9 + q*3 + 1];
            float e2 = theta[l*9 + q*3 + 2];
            float s0, c0; sincosf(0.5f*e0, &s0, &c0);
            float s1, c1; sincosf(0.5f*e1, &s1, &c1);
            float s2, c2; sincosf(0.5f*e2, &s2, &c2);
            // RX: [[c, -is],[-is, c]]
            gate1q(sr, si, q, c0, 0.f, 0.f, -s0, 0.f, -s0, c0, 0.f);
            // RY: [[c, -s],[s, c]]
            gate1q(sr, si, q, c1, 0.f, -s1, 0.f, s1, 0.f, c1, 0.f);
            // RZ: [[c - is, 0],[0, c + is]]
            gate1q(sr, si, q, c2, -s2, 0.f, 0.f, 0.f, 0.f, c2, s2);
        }
        // CNOTs: (0->1), (1->2), (2->0)
        gateCtrl(sr, si, 0, 1, 0.f,0.f, 1.f,0.f, 1.f,0.f, 0.f,0.f);
        gateCtrl(sr, si, 1, 2, 0.f,0.f, 1.f,0.f, 1.f,0.f, 0.f,0.f);
        gateCtrl(sr, si, 2, 0, 0.f,0.f, 1.f,0.f, 1.f,0.f, 0.f,0.f);
        // pk coupling: ctrl i -> target 3+j
        for (int i = 0; i < 3; ++i)
            for (int j = 0; j < 5; ++j)
                gateCRY(sr, si, i, 3 + j, theta[18 + l*15 + i*5 + j]);
        // pk local
        for (int j = 0; j < 5; ++j)
            gateRY(sr, si, 3 + j, theta[72 + l*5 + j]);
        // pd coupling: ctrl i -> target 8+k
        for (int i = 0; i < 3; ++i)
            for (int k = 0; k < 4; ++k)
                gateCRY(sr, si, i, 8 + k, theta[48 + l*12 + i*4 + k]);
        // pd local
        for (int k = 0; k < 4; ++k)
            gateRY(sr, si, 8 + k, theta[82 + l*4 + k]);
    }

    // <Z> on wires 3..11 (bit position 8-w for w in [0,9))
    float acc[9];
    #pragma unroll
    for (int w = 0; w < 9; ++w) acc[w] = 0.f;
    for (int i = tid; i < DIM; i += THREADS) {
        float p = sr[i]*sr[i] + si[i]*si[i];
        #pragma unroll
        for (int w = 0; w < 9; ++w)
            acc[w] += ((i >> (8 - w)) & 1) ? -p : p;
    }
    __syncthreads();   // done reading state; reuse sr as reduction scratch
    #pragma unroll
    for (int w = 0; w < 9; ++w) sr[w*THREADS + tid] = acc[w];
    __syncthreads();
    for (int s = THREADS/2; s > 0; s >>= 1) {
        if (tid < s) {
            #pragma unroll
            for (int w = 0; w < 9; ++w)
                sr[w*THREADS + tid] += sr[w*THREADS + tid + s];
        }
        __syncthreads();
    }

    if (tid < 9) {
        const float pk_lo[5] = {0.1f, 1.0f, 10.0f, 0.05f, 0.1f};
        const float pk_hi[5] = {5.0f, 20.0f, 100.0f, 2.0f, 10.0f};
        const float pd_lo[4] = {0.01f, 0.1f, 1.0f, 0.05f};
        const float pd_hi[4] = {1.0f, 5.0f, 50.0f, 2.0f};
        float raw = sr[tid*THREADS];
        float sv  = 0.5f * (raw + 1.0f);
        if (tid < 5) {
            out[b*5 + tid] = pk_lo[tid] + sv * (pk_hi[tid] - pk_lo[tid]);
        } else {
            int k = tid - 5;
            out[B*5 + b*4 + k] = pd_lo[k] + sv * (pd_hi[k] - pd_lo[k]);
        }
    }
}

extern "C" void kernel_launch(void* const* d_in, const int* in_sizes, int n_in,
                              void* d_out, int out_size, void* d_ws, size_t ws_size,
                              hipStream_t stream)
{
    // d_in[0]: subject_ids (int32, B) — unused by reference
    // d_in[1]: covariates  (f32, B*2)
    // d_in[2]: dose_intensities (f32, B)
    // d_in[3]: theta (f32, 90)
    const float* cov   = (const float*)d_in[1];
    const float* dose  = (const float*)d_in[2];
    const float* theta = (const float*)d_in[3];
    float* out = (float*)d_out;
    const int B = in_sizes[2];   // 512

    qsim_kernel<<<B, THREADS, 0, stream>>>(cov, dose, theta, out, B);
}

// Round 2
// 16.935 us; speedup vs baseline: 6.2998x; 6.2998x over previous
//
#include <hip/hip_runtime.h>
#include <math.h>

#define THREADS 256
#define SPB 32          // samples per block = THREADS/8

// Exact algebraic reduction of the 12-qubit circuit:
//   control register = wires 0-2 (8-dim), targets = wires 3-11 receive only
//   RY rotations diagonal in the control basis. Angles add; RY is real.
//   <Z_w> = sum_{c'} sum_{c1,c2} Re(A_{c',c1} conj(A_{c',c2}))
//           * prod_{v!=w} cos((a0_v(c1)-a0_v(c2))/2)
//           * cos((a0_w(c1)+a0_w(c2))/2 + a1_w(c'))
//   with A_{c',c} = V1_{c',c} * (V0 u_enc)_c.
__global__ __launch_bounds__(THREADS)
void qpkpd_kernel(const float* __restrict__ cov,
                  const float* __restrict__ dose,
                  const float* __restrict__ theta,
                  float* __restrict__ out, int B)
{
    __shared__ float sEr[24], sEi[24];        // Euler 2x2: idx=((l*3+q)*2+r)*2+c
    __shared__ float sV0r[64], sV0i[64];      // V0[row][col]
    __shared__ float sV1r[64], sV1i[64];
    __shared__ float sA0[72];                 // alpha0[w][c]
    __shared__ float sCA1[72], sSA1[72];      // cos/sin alpha1[w][c']
    __shared__ float sP[576], sQ[576];        // [w][c1*8+c2]

    const int t = threadIdx.x;

    // ---- phase 1: Euler 2x2 matrices (t<6); alpha tables (8<=t<80) ----
    if (t < 6) {
        int l = t / 3, q = t % 3;
        float e0 = theta[l*9 + q*3 + 0];
        float e1 = theta[l*9 + q*3 + 1];
        float e2 = theta[l*9 + q*3 + 2];
        float s0,c0,s1,c1,s2,c2;
        sincosf(0.5f*e0,&s0,&c0);
        sincosf(0.5f*e1,&s1,&c1);
        sincosf(0.5f*e2,&s2,&c2);
        // M = RY(e1)*RX(e0)
        float m00r =  c1*c0, m00i =  s1*s0;
        float m01r = -s1*c0, m01i = -c1*s0;
        float m10r =  s1*c0, m10i = -c1*s0;
        float m11r =  c1*c0, m11i = -s1*s0;
        int base = t*4;
        // E = RZ(e2)*M : row0 *= (c2 - i s2), row1 *= (c2 + i s2)
        sEr[base+0] = c2*m00r + s2*m00i;  sEi[base+0] = c2*m00i - s2*m00r;
        sEr[base+1] = c2*m01r + s2*m01i;  sEi[base+1] = c2*m01i - s2*m01r;
        sEr[base+2] = c2*m10r - s2*m10i;  sEi[base+2] = c2*m10i + s2*m10r;
        sEr[base+3] = c2*m11r - s2*m11i;  sEi[base+3] = c2*m11i + s2*m11r;
    }
    if (t >= 8 && t < 80) {
        int idx = t - 8;        // w*8 + c
        int w = idx >> 3, c = idx & 7;
        float b0 = (float)((c>>2)&1), b1 = (float)((c>>1)&1), b2 = (float)(c&1);
        float a0, a1;
        if (w < 5) {
            a0 = theta[72 + w] + b0*theta[18 + w] + b1*theta[18 + 5 + w] + b2*theta[18 + 10 + w];
            a1 = theta[77 + w] + b0*theta[33 + w] + b1*theta[33 + 5 + w] + b2*theta[33 + 10 + w];
        } else {
            int k = w - 5;
            a0 = theta[82 + k] + b0*theta[48 + k] + b1*theta[48 + 4 + k] + b2*theta[48 + 8 + k];
            a1 = theta[86 + k] + b0*theta[60 + k] + b1*theta[60 + 4 + k] + b2*theta[60 + 8 + k];
        }
        sA0[idx] = a0;
        float sa, ca; sincosf(a1, &sa, &ca);
        sCA1[idx] = ca; sSA1[idx] = sa;
    }
    __syncthreads();

    // ---- phase 2: V matrices (t<64); P/Q pair tables (64<=t<128) ----
    if (t < 64) {
        int r = t >> 3, c = t & 7;
        int rb0=(r>>2)&1, rb1=(r>>1)&1, rb2=r&1;
        int cb0=(c>>2)&1, cb1=(c>>1)&1, cb2=c&1;
        // CNOT chain (0->1),(1->2),(2->0) as a basis permutation of the row
        int nb1 = rb1 ^ rb0;
        int nb2 = rb2 ^ nb1;
        int nb0 = rb0 ^ nb2;
        int pr = (nb0<<2)|(nb1<<1)|nb2;
        #pragma unroll
        for (int l = 0; l < 2; ++l) {
            int i0 = (l*3+0)*4 + rb0*2 + cb0;
            int i1 = (l*3+1)*4 + rb1*2 + cb1;
            int i2 = (l*3+2)*4 + rb2*2 + cb2;
            float xr = sEr[i0], xi = sEi[i0];
            float yr = sEr[i1], yi = sEi[i1];
            float zr = xr*yr - xi*yi, zi = xr*yi + xi*yr;
            float wr = sEr[i2], wi = sEi[i2];
            float tr = zr*wr - zi*wi, ti = zr*wi + zi*wr;
            if (l == 0) { sV0r[pr*8+c] = tr; sV0i[pr*8+c] = ti; }
            else        { sV1r[pr*8+c] = tr; sV1i[pr*8+c] = ti; }
        }
    } else if (t < 128) {
        int p = t - 64;         // c1*8 + c2
        int c1 = p >> 3, c2 = p & 7;
        float cd[9], sh[9];
        #pragma unroll
        for (int v = 0; v < 9; ++v) {
            float a = sA0[v*8+c1], bq = sA0[v*8+c2];
            cd[v] = cosf(0.5f*(a-bq));
            sh[v] = 0.5f*(a+bq);
        }
        #pragma unroll
        for (int w = 0; w < 9; ++w) {
            float C = 1.0f;
            #pragma unroll
            for (int v = 0; v < 9; ++v) if (v != w) C *= cd[v];
            float ss, cc; sincosf(sh[w], &ss, &cc);
            sP[w*64+p] = C*cc;
            sQ[w*64+p] = C*ss;
        }
    }
    __syncthreads();

    // ---- main: 8 lanes (c') per sample ----
    int sl = t >> 3, lane = t & 7;
    int b = blockIdx.x * SPB + sl;
    if (b >= B) return;

    float x0 = cov[b*2+0], x1 = cov[b*2+1], x2 = dose[b];
    float f0[2], f1[2], f2[2];
    sincosf(0.5f*x0, &f0[1], &f0[0]);
    sincosf(0.5f*x1, &f1[1], &f1[0]);
    sincosf(0.5f*x2, &f2[1], &f2[0]);

    float u[8];
    #pragma unroll
    for (int c = 0; c < 8; ++c)
        u[c] = f0[(c>>2)&1] * f1[(c>>1)&1] * f2[c&1];

    // a = V0 * u_enc (u real)
    float ar[8], ai[8];
    #pragma unroll
    for (int c = 0; c < 8; ++c) {
        float rr = 0.f, ii = 0.f;
        #pragma unroll
        for (int k = 0; k < 8; ++k) {
            rr += sV0r[c*8+k]*u[k];
            ii += sV0i[c*8+k]*u[k];
        }
        ar[c] = rr; ai[c] = ii;
    }

    // v_c = V1[lane][c] * a_c
    float vr[8], vi[8];
    #pragma unroll
    for (int c = 0; c < 8; ++c) {
        float wr = sV1r[lane*8+c], wi = sV1i[lane*8+c];
        vr[c] = wr*ar[c] - wi*ai[c];
        vi[c] = wr*ai[c] + wi*ar[c];
    }

    float zP[9], zQ[9];
    #pragma unroll
    for (int w = 0; w < 9; ++w) { zP[w] = 0.f; zQ[w] = 0.f; }

    #pragma unroll
    for (int c1 = 0; c1 < 8; ++c1) {
        #pragma unroll
        for (int c2 = 0; c2 < 8; ++c2) {
            float R = vr[c1]*vr[c2] + vi[c1]*vi[c2];
            int p = c1*8+c2;
            #pragma unroll
            for (int w = 0; w < 9; ++w) {
                zP[w] += R * sP[w*64+p];
                zQ[w] += R * sQ[w*64+p];
            }
        }
    }

    float g[9];
    #pragma unroll
    for (int w = 0; w < 9; ++w)
        g[w] = sCA1[w*8+lane]*zP[w] - sSA1[w*8+lane]*zQ[w];

    // reduce over the 8 c'-lanes
    #pragma unroll
    for (int off = 1; off < 8; off <<= 1) {
        #pragma unroll
        for (int w = 0; w < 9; ++w)
            g[w] += __shfl_xor(g[w], off, 64);
    }

    if (lane == 0) {
        const float pk_lo[5] = {0.1f, 1.0f, 10.0f, 0.05f, 0.1f};
        const float pk_hi[5] = {5.0f, 20.0f, 100.0f, 2.0f, 10.0f};
        const float pd_lo[4] = {0.01f, 0.1f, 1.0f, 0.05f};
        const float pd_hi[4] = {1.0f, 5.0f, 50.0f, 2.0f};
        #pragma unroll
        for (int w = 0; w < 5; ++w) {
            float sv = 0.5f*(g[w]+1.0f);
            out[b*5+w] = pk_lo[w] + sv*(pk_hi[w]-pk_lo[w]);
        }
        #pragma unroll
        for (int k = 0; k < 4; ++k) {
            float sv = 0.5f*(g[5+k]+1.0f);
            out[B*5 + b*4 + k] = pd_lo[k] + sv*(pd_hi[k]-pd_lo[k]);
        }
    }
}

extern "C" void kernel_launch(void* const* d_in, const int* in_sizes, int n_in,
                              void* d_out, int out_size, void* d_ws, size_t ws_size,
                              hipStream_t stream)
{
    // d_in[0]: subject_ids (int32, B) — unused
    // d_in[1]: covariates  (f32, B*2)
    // d_in[2]: dose_intensities (f32, B)
    // d_in[3]: theta (f32, 90)
    const float* cov   = (const float*)d_in[1];
    const float* dose  = (const float*)d_in[2];
    const float* theta = (const float*)d_in[3];
    float* out = (float*)d_out;
    const int B = in_sizes[2];   // 512

    int grid = (B + SPB - 1) / SPB;   // 16
    qpkpd_kernel<<<grid, THREADS, 0, stream>>>(cov, dose, theta, out, B);
}

// Round 3
// 14.113 us; speedup vs baseline: 7.5594x; 1.1999x over previous
//
#include <hip/hip_runtime.h>
#include <math.h>

#define NW 9

// Fully factorized evaluation:
//   a = V0 * u_enc(sample)                       (8-dim complex, V0 theta-only)
//   g_w = sum_c |a_c|^2 G_w[c,c] + 2*sum_{c1<c2} (u*ReG - v*ImG)
//   G_w = P_w .* (V1^H diag(cos a1_w) V1) - Q_w .* (V1^H diag(sin a1_w) V1)
// All tables theta-only, built per block (replicated, cheap).
__global__ __launch_bounds__(64)
void qpkpd2_kernel(const float* __restrict__ cov,
                   const float* __restrict__ dose,
                   const float* __restrict__ theta,
                   float* __restrict__ out, int B)
{
    __shared__ float sEr[24], sEi[24];     // Euler 2x2 per (l,q)
    __shared__ float sA0[72];              // alpha0[w][c]
    __shared__ float sCA1[72], sSA1[72];   // cos/sin alpha1[w][c']
    __shared__ float sV1r[64], sV1i[64];
    __shared__ float4 sV0[32];             // [r][kk]: (re_k, im_k, re_k+1, im_k+1)
    __shared__ float4 sDiag[18];           // [w][2]: Gr diag, 8 floats per w
    __shared__ float4 sOff[126];           // [w][14]: 28 pairs (2Gr,2Gi)
    float* sV0f  = (float*)sV0;
    float* sDgf  = (float*)sDiag;
    float* sOfff = (float*)sOff;

    const int t = threadIdx.x;

    // ---------------- phase 1: Euler 2x2s + alpha tables ----------------
    if (t < 6) {
        int l = t / 3, q = t % 3;
        float e0 = theta[l*9 + q*3 + 0];
        float e1 = theta[l*9 + q*3 + 1];
        float e2 = theta[l*9 + q*3 + 2];
        float s0,c0,s1,c1,s2,c2;
        sincosf(0.5f*e0,&s0,&c0);
        sincosf(0.5f*e1,&s1,&c1);
        sincosf(0.5f*e2,&s2,&c2);
        // M = RY(e1)*RX(e0); E = RZ(e2)*M
        float m00r =  c1*c0, m00i =  s1*s0;
        float m01r = -s1*c0, m01i = -c1*s0;
        float m10r =  s1*c0, m10i = -c1*s0;
        float m11r =  c1*c0, m11i = -s1*s0;
        int base = t*4;
        sEr[base+0] = c2*m00r + s2*m00i;  sEi[base+0] = c2*m00i - s2*m00r;
        sEr[base+1] = c2*m01r + s2*m01i;  sEi[base+1] = c2*m01i - s2*m01r;
        sEr[base+2] = c2*m10r - s2*m10i;  sEi[base+2] = c2*m10i + s2*m10r;
        sEr[base+3] = c2*m11r - s2*m11i;  sEi[base+3] = c2*m11i + s2*m11r;
    }
    #pragma unroll
    for (int rep = 0; rep < 2; ++rep) {
        int idx = t + rep*64;
        if (idx < 72) {
            int w = idx >> 3, c = idx & 7;
            float b0 = (float)((c>>2)&1), b1 = (float)((c>>1)&1), b2 = (float)(c&1);
            float a0, a1;
            if (w < 5) {
                a0 = theta[72 + w] + b0*theta[18 + w] + b1*theta[23 + w] + b2*theta[28 + w];
                a1 = theta[77 + w] + b0*theta[33 + w] + b1*theta[38 + w] + b2*theta[43 + w];
            } else {
                int k = w - 5;
                a0 = theta[82 + k] + b0*theta[48 + k] + b1*theta[52 + k] + b2*theta[56 + k];
                a1 = theta[86 + k] + b0*theta[60 + k] + b1*theta[64 + k] + b2*theta[68 + k];
            }
            sA0[idx] = a0;
            float sa, ca; sincosf(a1, &sa, &ca);
            sCA1[idx] = ca; sSA1[idx] = sa;
        }
    }
    __syncthreads();

    // ---------------- phase 2: V0 / V1 (8x8) ----------------
    {
        int r = t >> 3, c = t & 7;
        int rb0=(r>>2)&1, rb1=(r>>1)&1, rb2=r&1;
        int cb0=(c>>2)&1, cb1=(c>>1)&1, cb2=c&1;
        // CNOT chain (0->1),(1->2),(2->0): row-basis permutation
        int nb1 = rb1 ^ rb0;
        int nb2 = rb2 ^ nb1;
        int nb0 = rb0 ^ nb2;
        int pr = (nb0<<2)|(nb1<<1)|nb2;
        #pragma unroll
        for (int l = 0; l < 2; ++l) {
            int i0 = (l*3+0)*4 + rb0*2 + cb0;
            int i1 = (l*3+1)*4 + rb1*2 + cb1;
            int i2 = (l*3+2)*4 + rb2*2 + cb2;
            float xr = sEr[i0], xi = sEi[i0];
            float yr = sEr[i1], yi = sEi[i1];
            float zr = xr*yr - xi*yi, zi = xr*yi + xi*yr;
            float wr = sEr[i2], wi = sEi[i2];
            float tr = zr*wr - zi*wi, ti = zr*wi + zi*wr;
            if (l == 0) { sV0f[pr*16 + c*2] = tr; sV0f[pr*16 + c*2 + 1] = ti; }
            else        { sV1r[pr*8+c] = tr; sV1i[pr*8+c] = ti; }
        }
    }
    __syncthreads();

    // ---------------- phase 3: G tables; thread t = (c1,c2) ----------------
    {
        int c1 = t >> 3, c2 = t & 7;
        float cd[9], sh[9];
        #pragma unroll
        for (int v = 0; v < 9; ++v) {
            float av = sA0[v*8+c1], bv = sA0[v*8+c2];
            cd[v] = cosf(0.5f*(av-bv));
            sh[v] = 0.5f*(av+bv);
        }
        float P[9], Q[9];
        #pragma unroll
        for (int w = 0; w < 9; ++w) {
            float C = 1.0f;
            #pragma unroll
            for (int v = 0; v < 9; ++v) if (v != w) C *= cd[v];
            float ss, cc; sincosf(sh[w], &ss, &cc);
            P[w] = C*cc; Q[w] = C*ss;
        }
        float pr[8], pi[8];
        #pragma unroll
        for (int cp = 0; cp < 8; ++cp) {
            float r1 = sV1r[cp*8+c1], i1 = sV1i[cp*8+c1];
            float r2 = sV1r[cp*8+c2], i2 = sV1i[cp*8+c2];
            pr[cp] = r1*r2 + i1*i2;
            pi[cp] = i1*r2 - r1*i2;
        }
        #pragma unroll
        for (int w = 0; w < 9; ++w) {
            float Kr=0.f, Ki=0.f, Lr=0.f, Li=0.f;
            #pragma unroll
            for (int cp = 0; cp < 8; ++cp) {
                float cw = sCA1[w*8+cp], sw = sSA1[w*8+cp];
                Kr += cw*pr[cp]; Ki += cw*pi[cp];
                Lr += sw*pr[cp]; Li += sw*pi[cp];
            }
            float Gr = P[w]*Kr - Q[w]*Lr;
            float Gi = P[w]*Ki - Q[w]*Li;
            if (c1 == c2) {
                sDgf[w*8 + c1] = Gr;
            } else if (c1 < c2) {
                int q = c1*(15-c1)/2 + (c2 - c1 - 1);
                sOfff[w*56 + q*2 + 0] = 2.0f*Gr;
                sOfff[w*56 + q*2 + 1] = 2.0f*Gi;
            }
        }
    }
    __syncthreads();

    // ---------------- phase 4: one thread = one sample ----------------
    int b = blockIdx.x*64 + t;
    if (b >= B) return;

    float x0 = cov[b*2+0], x1 = cov[b*2+1], x2 = dose[b];
    float f0[2], f1[2], f2[2];
    sincosf(0.5f*x0, &f0[1], &f0[0]);
    sincosf(0.5f*x1, &f1[1], &f1[0]);
    sincosf(0.5f*x2, &f2[1], &f2[0]);
    float u[8];
    #pragma unroll
    for (int c = 0; c < 8; ++c)
        u[c] = f0[(c>>2)&1] * f1[(c>>1)&1] * f2[c&1];

    // a = V0 * u  (u real) — broadcast float4 LDS reads
    float ar[8], ai[8];
    #pragma unroll
    for (int r = 0; r < 8; ++r) {
        float4 m0 = sV0[r*4+0], m1 = sV0[r*4+1], m2 = sV0[r*4+2], m3 = sV0[r*4+3];
        ar[r] = m0.x*u[0] + m0.z*u[1] + m1.x*u[2] + m1.z*u[3]
              + m2.x*u[4] + m2.z*u[5] + m3.x*u[6] + m3.z*u[7];
        ai[r] = m0.y*u[0] + m0.w*u[1] + m1.y*u[2] + m1.w*u[3]
              + m2.y*u[4] + m2.w*u[5] + m3.y*u[6] + m3.w*u[7];
    }

    float d[8];
    #pragma unroll
    for (int c = 0; c < 8; ++c) d[c] = ar[c]*ar[c] + ai[c]*ai[c];

    float uq[28], vq[28];
    {
        int q = 0;
        #pragma unroll
        for (int c1 = 0; c1 < 8; ++c1) {
            #pragma unroll
            for (int c2 = c1+1; c2 < 8; ++c2) {
                uq[q] = ar[c1]*ar[c2] + ai[c1]*ai[c2];
                vq[q] = ai[c1]*ar[c2] - ar[c1]*ai[c2];
                ++q;
            }
        }
    }

    const float pk_lo[5] = {0.1f, 1.0f, 10.0f, 0.05f, 0.1f};
    const float pk_hi[5] = {5.0f, 20.0f, 100.0f, 2.0f, 10.0f};
    const float pd_lo[4] = {0.01f, 0.1f, 1.0f, 0.05f};
    const float pd_hi[4] = {1.0f, 5.0f, 50.0f, 2.0f};

    #pragma unroll
    for (int w = 0; w < NW; ++w) {
        float4 d0 = sDiag[w*2+0], d1 = sDiag[w*2+1];
        float g = d[0]*d0.x + d[1]*d0.y + d[2]*d0.z + d[3]*d0.w
                + d[4]*d1.x + d[5]*d1.y + d[6]*d1.z + d[7]*d1.w;
        #pragma unroll
        for (int q4 = 0; q4 < 14; ++q4) {
            float4 o = sOff[w*14 + q4];
            g += uq[2*q4+0]*o.x - vq[2*q4+0]*o.y
               + uq[2*q4+1]*o.z - vq[2*q4+1]*o.w;
        }
        float sv = 0.5f*(g + 1.0f);
        if (w < 5) out[b*5 + w]           = pk_lo[w]   + sv*(pk_hi[w]  - pk_lo[w]);
        else       out[B*5 + b*4 + (w-5)] = pd_lo[w-5] + sv*(pd_hi[w-5]- pd_lo[w-5]);
    }
}

extern "C" void kernel_launch(void* const* d_in, const int* in_sizes, int n_in,
                              void* d_out, int out_size, void* d_ws, size_t ws_size,
                              hipStream_t stream)
{
    // d_in[0]: subject_ids (int32, B) — unused
    // d_in[1]: covariates  (f32, B*2)
    // d_in[2]: dose_intensities (f32, B)
    // d_in[3]: theta (f32, 90)
    const float* cov   = (const float*)d_in[1];
    const float* dose  = (const float*)d_in[2];
    const float* theta = (const float*)d_in[3];
    float* out = (float*)d_out;
    const int B = in_sizes[2];   // 512

    int grid = (B + 63) / 64;    // 8 blocks x 64 threads: one wave per CU
    qpkpd2_kernel<<<grid, 64, 0, stream>>>(cov, dose, theta, out, B);
}